// Round 12
// baseline (317.472 us; speedup 1.0000x reference)
//
#include <hip/hip_runtime.h>

#define F_IN 128
#define HID 64
#define HEADS 4
#define NC 8

typedef __bf16 bf16_t;
typedef bf16_t bf16x8 __attribute__((ext_vector_type(8)));
typedef float f32x4 __attribute__((ext_vector_type(4)));

union BF8 { bf16x8 v; ushort u[8]; };

// ---------------------------------------------------------------- helpers

__device__ __forceinline__ ushort f2bf(float f) {      // RNE round to bf16
    uint u = __float_as_uint(f);
    return (ushort)((u + 0x7fffu + ((u >> 16) & 1u)) >> 16);
}
__device__ __forceinline__ float bf2f(ushort h) {
    return __uint_as_float(((uint)h) << 16);
}
__device__ __forceinline__ float edgew(float e) {      // exp(leaky_relu(e, 0.2))
    e = (e > 0.f) ? e : 0.2f * e;
    return __expf(e);
}

// ---------------------------------------------------------------- setup
// w1p pack (for postgemm, hi only): [h(4)][ct(4)][kc(4)][lane(64)][j(8)]
//   B[k][c] of head h: k=kc*32+(lane>>4)*8+j, c=ct*16+(lane&15), global col=h*64+c
// w2 pack: [ct(4)][kc(8)][lane(64)][j(8)]
// ps/pd[h][k] = sum_c W1[k][h*64+c] * att{s,d}1[h][c]
__global__ void k_setup(const float* __restrict__ W1, const float* __restrict__ W2,
                        const float* __restrict__ atts1, const float* __restrict__ attd1,
                        ushort* __restrict__ w1p,
                        ushort* __restrict__ w2hi, ushort* __restrict__ w2lo,
                        float* __restrict__ ps, float* __restrict__ pd,
                        int* __restrict__ deg, int N, int* __restrict__ counts, int NG) {
    int i = blockIdx.x * blockDim.x + threadIdx.x;
    if (i < N) deg[i] = 1;              // self loop contributes 1
    if (i < NG) counts[i] = 0;
    if (i < 128 * 256) {
        int k = i >> 8, n = i & 255;
        int h = n >> 6, c = n & 63;
        int ct = c >> 4, lc = c & 15, kc = k >> 5, ls = (k >> 3) & 3, j = k & 7;
        size_t off = ((((size_t)h * 4 + ct) * 4 + kc) * 64 + (ls * 16 + lc)) * 8 + j;
        w1p[off] = f2bf(W1[i]);
    }
    if (i < 256 * 64) {
        int k = i >> 6, n = i & 63;
        int ct = n >> 4, c = n & 15, kc = k >> 5, ls = (k >> 3) & 3, j = k & 7;
        size_t off = (((size_t)ct * 8 + kc) * 64 + (ls * 16 + c)) * 8 + j;
        float w = W2[i];
        ushort hi = f2bf(w);
        w2hi[off] = hi; w2lo[off] = f2bf(w - bf2f(hi));
    }
    if (i < 512) {                      // i = h*128 + k
        int h = i >> 7, k = i & 127;
        float s = 0.f, d = 0.f;
        for (int c = 0; c < 64; c++) {
            float w = W1[k * 256 + h * 64 + c];
            s += w * atts1[h * 64 + c];
            d += w * attd1[h * 64 + c];
        }
        ps[i] = s; pd[i] = d;
    }
}

// fused: edge degree count + batch count
__global__ void k_count(const int* __restrict__ ei, int E, int* __restrict__ deg,
                        const int* __restrict__ batch, int N, int* __restrict__ counts) {
    int i = blockIdx.x * blockDim.x + threadIdx.x;
    if (i < E) atomicAdd(&deg[ei[E + i]], 1);   // dst row
    if (i < N) atomicAdd(&counts[batch[i]], 1);
}

__global__ __launch_bounds__(1024) void k_scan_part(const int* __restrict__ v,
                                                    int* __restrict__ excl,
                                                    int* __restrict__ bsum, int n) {
    __shared__ int buf[1024];
    int tid = threadIdx.x;
    int i = blockIdx.x * 1024 + tid;
    int val = (i < n) ? v[i] : 0;
    buf[tid] = val;
    __syncthreads();
    for (int off = 1; off < 1024; off <<= 1) {
        int t = (tid >= off) ? buf[tid - off] : 0;
        __syncthreads();
        buf[tid] += t;
        __syncthreads();
    }
    if (i < n) excl[i] = buf[tid] - val;
    if (tid == 1023) bsum[blockIdx.x] = buf[1023];
}

// block 0: scan bsum[nb] -> boff; block 1: scan counts[ng] -> gstart[0..ng]
__global__ __launch_bounds__(1024) void k_scan_small2(const int* __restrict__ bsum,
                                                      int* __restrict__ boff, int nb,
                                                      int* __restrict__ total_out,
                                                      const int* __restrict__ counts,
                                                      int* __restrict__ gstart, int ng) {
    __shared__ int buf[1024];
    int tid = threadIdx.x;
    const int* src = (blockIdx.x == 0) ? bsum : counts;
    int cnt = (blockIdx.x == 0) ? nb : ng;
    int val = (tid < cnt) ? src[tid] : 0;
    buf[tid] = val;
    __syncthreads();
    for (int off = 1; off < 1024; off <<= 1) {
        int t = (tid >= off) ? buf[tid - off] : 0;
        __syncthreads();
        buf[tid] += t;
        __syncthreads();
    }
    if (blockIdx.x == 0) {
        if (tid < cnt) boff[tid] = buf[tid] - val;
        if (tid == 1023) total_out[0] = buf[1023];
    } else {
        if (tid < cnt) gstart[tid] = buf[tid] - val;
        if (tid == 1023) gstart[ng] = buf[1023];
    }
}

__global__ void k_scan_add_self(int* __restrict__ rowstart, const int* __restrict__ boff,
                                int* __restrict__ cursor, int* __restrict__ csr, int n) {
    int i = blockIdx.x * blockDim.x + threadIdx.x;
    if (i < n) {
        int rs = rowstart[i] + boff[i >> 10];
        rowstart[i] = rs;
        csr[rs] = i;          // self loop first
        cursor[i] = 1;
    }
}

__global__ void k_scatter(const int* __restrict__ ei, int E, const int* __restrict__ rowstart,
                          int* __restrict__ cursor, int* __restrict__ csr) {
    int e = blockIdx.x * blockDim.x + threadIdx.x;
    if (e < E) {
        int d = ei[E + e], s = ei[e];
        int pos = atomicAdd(&cursor[d], 1);
        csr[rowstart[d] + pos] = s;
    }
}

// ---------------------------------------------------------------- proj: xb = bf16(x); as1/ad1 = x . ps/pd
// wave per node: lane covers 2 channels (float2, fully coalesced)
__global__ __launch_bounds__(256) void k_proj(const float* __restrict__ x,
                                              const float* __restrict__ ps,
                                              const float* __restrict__ pd,
                                              ushort* __restrict__ xb,
                                              float* __restrict__ as1, float* __restrict__ ad1,
                                              int N) {
    __shared__ float lps[512], lpd[512];
    int tid = threadIdx.x;
    lps[tid] = ps[tid]; lps[tid + 256] = ps[tid + 256];
    lpd[tid] = pd[tid]; lpd[tid + 256] = pd[tid + 256];
    __syncthreads();
    int wid = tid >> 6, lane = tid & 63;
    int n = blockIdx.x * 4 + wid;
    if (n >= N) return;
    float2 xv = *(const float2*)(x + (size_t)n * 128 + lane * 2);
    ushort2 xbv; xbv.x = f2bf(xv.x); xbv.y = f2bf(xv.y);
    *(ushort2*)(xb + (size_t)n * 128 + lane * 2) = xbv;
    float s[4], d[4];
    #pragma unroll
    for (int h = 0; h < 4; h++) {
        s[h] = xv.x * lps[h * 128 + 2 * lane] + xv.y * lps[h * 128 + 2 * lane + 1];
        d[h] = xv.x * lpd[h * 128 + 2 * lane] + xv.y * lpd[h * 128 + 2 * lane + 1];
    }
    #pragma unroll
    for (int off = 1; off < 64; off <<= 1) {
        #pragma unroll
        for (int h = 0; h < 4; h++) {
            s[h] += __shfl_xor(s[h], off);
            d[h] += __shfl_xor(d[h], off);
        }
    }
    if (lane == 0) {
        float4 sv = {s[0], s[1], s[2], s[3]};
        float4 dv = {d[0], d[1], d[2], d[3]};
        *(float4*)(as1 + (size_t)n * 4) = sv;
        *(float4*)(ad1 + (size_t)n * 4) = dv;
    }
}

// ---------------------------------------------------------------- fused edgew + x-space aggregation (layer 1)
// out1_i = (sum_j alpha_ij x_j) @ W1  — gather 256B x rows instead of 512B h1 rows.
// 1 wave/node. Phase A: lane-per-edge weights -> LDS. Phase B: 4 edges per load instr
// (16 lanes x 16B cover a 256B row); acc[4 heads][8 ch] in regs; writes xaggb[h][n][128] (with 1/denom).
__global__ __launch_bounds__(256) void k_fagg1(const ushort* __restrict__ xb,
                                               const float* __restrict__ as1,
                                               const float* __restrict__ ad1,
                                               const int* __restrict__ rowstart,
                                               const int* __restrict__ csr,
                                               ushort* __restrict__ xaggb, int N) {
    __shared__ float lw[4][256];
    __shared__ int   lsrc[4][64];
    int wid = threadIdx.x >> 6, lane = threadIdx.x & 63;
    int n = blockIdx.x * 4 + wid;
    if (n >= N) return;
    int beg = rowstart[n], end = rowstart[n + 1];
    float4 adv = *(const float4*)(ad1 + (size_t)n * 4);
    int g = lane >> 4, li = lane & 15;
    int c0 = li * 8;
    float s0 = 0.f, s1 = 0.f, s2 = 0.f, s3 = 0.f;
    float a[4][8];
    #pragma unroll
    for (int h = 0; h < 4; h++)
        #pragma unroll
        for (int c = 0; c < 8; c++) a[h][c] = 0.f;

    for (int jc = beg; jc < end; jc += 64) {
        // phase A: lane-per-edge weights
        int j = jc + lane;
        float4 wv = {0.f, 0.f, 0.f, 0.f};
        int src = 0;
        if (j < end) {
            src = csr[j];
            float4 av = *(const float4*)(as1 + (size_t)src * 4);
            wv.x = edgew(av.x + adv.x); wv.y = edgew(av.y + adv.y);
            wv.z = edgew(av.z + adv.z); wv.w = edgew(av.w + adv.w);
            s0 += wv.x; s1 += wv.y; s2 += wv.z; s3 += wv.w;
        }
        *(float4*)&lw[wid][lane * 4] = wv;
        lsrc[wid][lane] = src;
        // phase B: 4 rows in flight per iteration (pad slots have w=0)
        int cnt = min(64, end - jc);
        int iters = (cnt + 3) >> 2;
        for (int t = 0; t < iters; t += 4) {
            #pragma unroll
            for (int u = 0; u < 4; u++) {
                int tt = t + u;
                if (tt < iters) {
                    int e = tt * 4 + g;
                    int sr = lsrc[wid][e];
                    float w0 = lw[wid][e * 4 + 0], w1 = lw[wid][e * 4 + 1];
                    float w2 = lw[wid][e * 4 + 2], w3 = lw[wid][e * 4 + 3];
                    uint4 hv = *(const uint4*)(xb + (size_t)sr * 128 + c0);
                    float v[8];
                    v[0] = bf2f((ushort)(hv.x & 0xffffu)); v[1] = bf2f((ushort)(hv.x >> 16));
                    v[2] = bf2f((ushort)(hv.y & 0xffffu)); v[3] = bf2f((ushort)(hv.y >> 16));
                    v[4] = bf2f((ushort)(hv.z & 0xffffu)); v[5] = bf2f((ushort)(hv.z >> 16));
                    v[6] = bf2f((ushort)(hv.w & 0xffffu)); v[7] = bf2f((ushort)(hv.w >> 16));
                    #pragma unroll
                    for (int c = 0; c < 8; c++) {
                        a[0][c] += w0 * v[c];
                        a[1][c] += w1 * v[c];
                        a[2][c] += w2 * v[c];
                        a[3][c] += w3 * v[c];
                    }
                }
            }
        }
    }
    // cross-group reduce (groups hold disjoint edge subsets)
    #pragma unroll
    for (int h = 0; h < 4; h++)
        #pragma unroll
        for (int c = 0; c < 8; c++) {
            a[h][c] += __shfl_xor(a[h][c], 16);
            a[h][c] += __shfl_xor(a[h][c], 32);
        }
    // softmax denominators
    #pragma unroll
    for (int off = 1; off < 64; off <<= 1) {
        s0 += __shfl_xor(s0, off); s1 += __shfl_xor(s1, off);
        s2 += __shfl_xor(s2, off); s3 += __shfl_xor(s3, off);
    }
    if (g == 0) {
        float inv[4] = {1.f / s0, 1.f / s1, 1.f / s2, 1.f / s3};
        #pragma unroll
        for (int h = 0; h < 4; h++) {
            uint4 ov;
            ov.x = (uint)f2bf(a[h][0] * inv[h]) | ((uint)f2bf(a[h][1] * inv[h]) << 16);
            ov.y = (uint)f2bf(a[h][2] * inv[h]) | ((uint)f2bf(a[h][3] * inv[h]) << 16);
            ov.z = (uint)f2bf(a[h][4] * inv[h]) | ((uint)f2bf(a[h][5] * inv[h]) << 16);
            ov.w = (uint)f2bf(a[h][6] * inv[h]) | ((uint)f2bf(a[h][7] * inv[h]) << 16);
            *(uint4*)(xaggb + ((size_t)h * N + n) * 128 + c0) = ov;
        }
    }
}

// ---------------------------------------------------------------- postgemm: out1 = relu(xagg[h] @ W1[:,h] + b1)
// blockIdx.y = head. Block 256 rows; wave 64 rows; 4 mt x 4 ct x 4 kc MFMA.
__global__ __launch_bounds__(256) void k_postgemm(const ushort* __restrict__ xaggb,
                                                  const ushort* __restrict__ w1p,
                                                  const float* __restrict__ b1,
                                                  ushort* __restrict__ out1b, int N) {
    __shared__ __align__(16) ushort lw[8192];   // 16 KB: this head's W pack
    int tid = threadIdx.x;
    int h = blockIdx.y;
    {
        float4* dh = (float4*)lw; const float4* sh = (const float4*)(w1p + (size_t)h * 8192);
        #pragma unroll
        for (int i = 0; i < 4; i++) dh[tid + i * 256] = sh[tid + i * 256];
    }
    __syncthreads();
    int w = tid >> 6, l = tid & 63;
    int lc = l & 15, lk = l >> 4;
    int rbase = blockIdx.x * 256 + w * 64;
    const ushort* abase = xaggb + (size_t)h * N * 128;

    f32x4 acc[4][4];
    #pragma unroll
    for (int mt = 0; mt < 4; mt++)
        #pragma unroll
        for (int ct = 0; ct < 4; ct++) acc[mt][ct] = (f32x4){0.f, 0.f, 0.f, 0.f};

    #pragma unroll
    for (int kc = 0; kc < 4; kc++) {
        BF8 a[4];
        #pragma unroll
        for (int mt = 0; mt < 4; mt++) {
            int row = rbase + mt * 16 + lc;
            if (row < N) {
                a[mt].v = *(const bf16x8*)(abase + (size_t)row * 128 + kc * 32 + lk * 8);
            } else {
                #pragma unroll
                for (int j = 0; j < 8; j++) a[mt].u[j] = 0;
            }
        }
        #pragma unroll
        for (int ct = 0; ct < 4; ct++) {
            bf16x8 bv = *(const bf16x8*)(lw + ((ct * 4 + kc) * 64 + l) * 8);
            #pragma unroll
            for (int mt = 0; mt < 4; mt++) {
                acc[mt][ct] = __builtin_amdgcn_mfma_f32_16x16x32_bf16(a[mt].v, bv, acc[mt][ct], 0, 0, 0);
            }
        }
    }
    // epilogue: C/D layout col=lane&15, row=(lane>>4)*4+reg; fused bias+relu
    #pragma unroll
    for (int mt = 0; mt < 4; mt++) {
        int rowb = rbase + mt * 16 + lk * 4;
        #pragma unroll
        for (int ct = 0; ct < 4; ct++) {
            int col = h * 64 + ct * 16 + lc;
            float bb = b1[col];
            #pragma unroll
            for (int r = 0; r < 4; r++) {
                int row = rowb + r;
                if (row < N) {
                    float o = acc[mt][ct][r] + bb;
                    out1b[(size_t)row * 256 + col] = f2bf(o > 0.f ? o : 0.f);
                }
            }
        }
    }
}

// ---------------------------------------------------------------- layer-2 GEMM (MFMA) + fused att
__global__ __launch_bounds__(256) void k_gemm2(const ushort* __restrict__ xin,
                                               const ushort* __restrict__ w2hi,
                                               const ushort* __restrict__ w2lo,
                                               const float* __restrict__ atts,
                                               const float* __restrict__ attd,
                                               ushort* __restrict__ h2b,
                                               float* __restrict__ as2, float* __restrict__ ad2,
                                               int N) {
    __shared__ __align__(16) ushort lhi[16384];
    __shared__ __align__(16) ushort llo[16384];
    int tid = threadIdx.x;
    {
        float4* dh = (float4*)lhi; const float4* sh = (const float4*)w2hi;
        float4* dl = (float4*)llo; const float4* sl = (const float4*)w2lo;
        #pragma unroll
        for (int i = 0; i < 8; i++) {
            dh[tid + i * 256] = sh[tid + i * 256];
            dl[tid + i * 256] = sl[tid + i * 256];
        }
    }
    __syncthreads();
    int w = tid >> 6, l = tid & 63;
    int lc = l & 15, lk = l >> 4;
    int rbase = blockIdx.x * 256 + w * 64;

    f32x4 acc[4][4];
    #pragma unroll
    for (int mt = 0; mt < 4; mt++)
        #pragma unroll
        for (int ct = 0; ct < 4; ct++) acc[mt][ct] = (f32x4){0.f, 0.f, 0.f, 0.f};

    #pragma unroll
    for (int kc = 0; kc < 8; kc++) {
        BF8 a[4];
        #pragma unroll
        for (int mt = 0; mt < 4; mt++) {
            int row = rbase + mt * 16 + lc;
            if (row < N) {
                a[mt].v = *(const bf16x8*)(xin + (size_t)row * 256 + kc * 32 + lk * 8);
            } else {
                #pragma unroll
                for (int j = 0; j < 8; j++) a[mt].u[j] = 0;
            }
        }
        #pragma unroll
        for (int ct = 0; ct < 4; ct++) {
            int boff = ((ct * 8 + kc) * 64 + l) * 8;
            bf16x8 bhi = *(const bf16x8*)(lhi + boff);
            bf16x8 blo = *(const bf16x8*)(llo + boff);
            #pragma unroll
            for (int mt = 0; mt < 4; mt++) {
                acc[mt][ct] = __builtin_amdgcn_mfma_f32_16x16x32_bf16(a[mt].v, bhi, acc[mt][ct], 0, 0, 0);
                acc[mt][ct] = __builtin_amdgcn_mfma_f32_16x16x32_bf16(a[mt].v, blo, acc[mt][ct], 0, 0, 0);
            }
        }
    }
    #pragma unroll
    for (int mt = 0; mt < 4; mt++) {
        int rowb = rbase + mt * 16 + lk * 4;
        #pragma unroll
        for (int ct = 0; ct < 4; ct++) {
            int col = ct * 16 + lc;
            #pragma unroll
            for (int r = 0; r < 4; r++) {
                int row = rowb + r;
                if (row < N) h2b[(size_t)row * 64 + col] = f2bf(acc[mt][ct][r]);
            }
        }
        float s[4] = {0.f, 0.f, 0.f, 0.f}, d[4] = {0.f, 0.f, 0.f, 0.f};
        #pragma unroll
        for (int ct = 0; ct < 4; ct++) {
            int col = ct * 16 + lc;
            float av = atts[col], dv = attd[col];
            #pragma unroll
            for (int r = 0; r < 4; r++) { s[r] += acc[mt][ct][r] * av; d[r] += acc[mt][ct][r] * dv; }
        }
        #pragma unroll
        for (int r = 0; r < 4; r++) {
            #pragma unroll
            for (int off = 1; off < 16; off <<= 1) {
                s[r] += __shfl_xor(s[r], off);
                d[r] += __shfl_xor(d[r], off);
            }
        }
        if (lc == 0) {
            #pragma unroll
            for (int r = 0; r < 4; r++) {
                int row = rowb + r;
                if (row < N) { as2[row] = s[r]; ad2[row] = d[r]; }
            }
        }
    }
}

// ---------------------------------------------------------------- fused edgew + aggregation, layer 2
__global__ __launch_bounds__(256) void k_fagg2(const ushort* __restrict__ h2b,
                                               const float* __restrict__ as2,
                                               const float* __restrict__ ad2,
                                               const int* __restrict__ rowstart,
                                               const int* __restrict__ csr,
                                               const float* __restrict__ b2,
                                               float* __restrict__ out2, int N) {
    __shared__ float lw[4][64];
    __shared__ int   lsrc[4][64];
    int wid = threadIdx.x >> 6, lane = threadIdx.x & 63;
    int n = blockIdx.x * 4 + wid;
    if (n >= N) return;
    int beg = rowstart[n], end = rowstart[n + 1];
    float adv = ad2[n];
    int g = lane >> 3, li = lane & 7;
    int c0 = li * 8;
    float ss = 0.f;
    float a[8];
    #pragma unroll
    for (int i = 0; i < 8; i++) a[i] = 0.f;

    for (int jc = beg; jc < end; jc += 64) {
        int j = jc + lane;
        float wgt = 0.f;
        int src = 0;
        if (j < end) {
            src = csr[j];
            wgt = edgew(as2[src] + adv);
            ss += wgt;
        }
        lw[wid][lane] = wgt;
        lsrc[wid][lane] = src;
        int cnt = min(64, end - jc);
        int groups = (cnt + 7) >> 3;
        for (int t = 0; t < groups; t += 2) {
            #pragma unroll
            for (int u = 0; u < 2; u++) {
                int tt = t + u;
                if (tt < groups) {
                    int e = tt * 8 + g;
                    int sr = lsrc[wid][e];
                    float wv = lw[wid][e];
                    uint4 hv = *(const uint4*)(h2b + (size_t)sr * 64 + c0);
                    a[0] += wv * bf2f((ushort)(hv.x & 0xffffu));
                    a[1] += wv * bf2f((ushort)(hv.x >> 16));
                    a[2] += wv * bf2f((ushort)(hv.y & 0xffffu));
                    a[3] += wv * bf2f((ushort)(hv.y >> 16));
                    a[4] += wv * bf2f((ushort)(hv.z & 0xffffu));
                    a[5] += wv * bf2f((ushort)(hv.z >> 16));
                    a[6] += wv * bf2f((ushort)(hv.w & 0xffffu));
                    a[7] += wv * bf2f((ushort)(hv.w >> 16));
                }
            }
        }
    }
    #pragma unroll
    for (int i = 0; i < 8; i++) {
        a[i] += __shfl_xor(a[i], 8);
        a[i] += __shfl_xor(a[i], 16);
        a[i] += __shfl_xor(a[i], 32);
    }
    #pragma unroll
    for (int off = 1; off < 64; off <<= 1) ss += __shfl_xor(ss, off);
    float inv = 1.f / ss;
    if (g == 0) {
        const float4* bv = (const float4*)(b2 + c0);
        float4 bA = bv[0], bB = bv[1];
        float4 oA, oB;
        oA.x = fmaxf(a[0] * inv + bA.x, 0.f); oA.y = fmaxf(a[1] * inv + bA.y, 0.f);
        oA.z = fmaxf(a[2] * inv + bA.z, 0.f); oA.w = fmaxf(a[3] * inv + bA.w, 0.f);
        oB.x = fmaxf(a[4] * inv + bB.x, 0.f); oB.y = fmaxf(a[5] * inv + bB.y, 0.f);
        oB.z = fmaxf(a[6] * inv + bB.z, 0.f); oB.w = fmaxf(a[7] * inv + bB.w, 0.f);
        float* op = out2 + (size_t)n * 64 + c0;
        *(float4*)op = oA;
        *(float4*)(op + 4) = oB;
    }
}

// ---------------------------------------------------------------- pool + final linear

__global__ __launch_bounds__(64) void k_pool(const float* __restrict__ out2,
                                             const int* __restrict__ gstart,
                                             const float* __restrict__ lin_w,
                                             const float* __restrict__ lin_b,
                                             float* __restrict__ out, int NG) {
    __shared__ float mean[64];
    int g = blockIdx.x;
    int lane = threadIdx.x;
    int beg = gstart[g], end = gstart[g + 1];
    float s = 0.f;
    for (int n = beg; n < end; n++) s += out2[(size_t)n * 64 + lane];
    float cnt = (float)(end - beg);
    mean[lane] = s / fmaxf(cnt, 1.f);
    __syncthreads();
    if (lane < NC) {
        float acc = lin_b[lane];
        #pragma unroll
        for (int c = 0; c < 64; c++) acc += mean[c] * lin_w[c * NC + lane];
        out[g * NC + lane] = acc;
    }
}

// ---------------------------------------------------------------- launch

extern "C" void kernel_launch(void* const* d_in, const int* in_sizes, int n_in,
                              void* d_out, int out_size, void* d_ws, size_t ws_size,
                              hipStream_t stream) {
    const float* x      = (const float*)d_in[0];
    const int*   ei     = (const int*)d_in[1];
    const int*   batch  = (const int*)d_in[2];
    const float* W1     = (const float*)d_in[3];
    const float* att_s1 = (const float*)d_in[4];
    const float* att_d1 = (const float*)d_in[5];
    const float* b1     = (const float*)d_in[6];
    const float* W2     = (const float*)d_in[7];
    const float* att_s2 = (const float*)d_in[8];
    const float* att_d2 = (const float*)d_in[9];
    const float* b2     = (const float*)d_in[10];
    const float* lin_w  = (const float*)d_in[11];
    const float* lin_b  = (const float*)d_in[12];
    float* out = (float*)d_out;

    const int N  = in_sizes[0] / F_IN;   // 50000
    const int E  = in_sizes[1] / 2;      // 800000
    const int NG = out_size / NC;        // 512
    const int NE = E + N;
    const int NB = (N + 1023) / 1024;    // scan blocks

    char* p = (char*)d_ws;
    auto alloc = [&](size_t bytes) { char* r = p; p += (bytes + 255) & ~(size_t)255; return r; };
    ushort* xb      = (ushort*)alloc(sizeof(ushort) * (size_t)N * 128);   // 12.8MB; out2 aliases later
    ushort* xaggb   = (ushort*)alloc(sizeof(ushort) * (size_t)N * 512);   // 51.2MB [h][n][128]
    ushort* out1b   = (ushort*)alloc(sizeof(ushort) * (size_t)N * 256);   // 25.6MB
    ushort* h2b     = (ushort*)alloc(sizeof(ushort) * (size_t)N * 64);    // 6.4MB
    float*  as1     = (float*)alloc(sizeof(float) * (size_t)N * 4);
    float*  ad1     = (float*)alloc(sizeof(float) * (size_t)N * 4);
    float*  as2     = (float*)alloc(sizeof(float) * (size_t)N);
    float*  ad2     = (float*)alloc(sizeof(float) * (size_t)N);
    int*    rowstart= (int*)alloc(sizeof(int) * (size_t)(N + 1));
    int*    itmp    = (int*)alloc(sizeof(int) * (size_t)N);      // deg, then cursor
    int*    csr     = (int*)alloc(sizeof(int) * (size_t)NE);
    int*    counts  = (int*)alloc(sizeof(int) * (size_t)NG);
    int*    gstart  = (int*)alloc(sizeof(int) * (size_t)(NG + 1));
    int*    bsum    = (int*)alloc(sizeof(int) * 1024);
    int*    boff    = (int*)alloc(sizeof(int) * 1024);
    ushort* w1p     = (ushort*)alloc(sizeof(ushort) * 32768);
    ushort* w2hi    = (ushort*)alloc(sizeof(ushort) * 16384);
    ushort* w2lo    = (ushort*)alloc(sizeof(ushort) * 16384);
    float*  psv     = (float*)alloc(sizeof(float) * 512);
    float*  pdv     = (float*)alloc(sizeof(float) * 512);
    float*  out2    = (float*)xb;    // alias: xb dead after k_fagg1; N*64*4 == N*128*2

    int bs = 256;
    // setup: W packs + projection vectors + deg/counts init
    k_setup<<<(N + bs - 1) / bs, bs, 0, stream>>>(W1, W2, att_s1, att_d1, w1p, w2hi, w2lo,
                                                  psv, pdv, itmp, N, counts, NG);
    k_count<<<(E + bs - 1) / bs, bs, 0, stream>>>(ei, E, itmp, batch, N, counts);
    k_scan_part<<<NB, 1024, 0, stream>>>(itmp, rowstart, bsum, N);
    k_scan_small2<<<2, 1024, 0, stream>>>(bsum, boff, NB, rowstart + N, counts, gstart, NG);
    k_scan_add_self<<<(N + 1023) / 1024, 1024, 0, stream>>>(rowstart, boff, itmp, csr, N);
    k_scatter<<<(E + bs - 1) / bs, bs, 0, stream>>>(ei, E, rowstart, itmp, csr);

    // layer 1: proj -> x-space aggregation -> post-GEMM
    k_proj<<<(N + 3) / 4, 256, 0, stream>>>(x, psv, pdv, xb, as1, ad1, N);
    k_fagg1<<<(N + 3) / 4, 256, 0, stream>>>(xb, as1, ad1, rowstart, csr, xaggb, N);
    k_postgemm<<<dim3((N + 255) / 256, 4), 256, 0, stream>>>(xaggb, w1p, b1, out1b, N);

    // layer 2
    k_gemm2<<<(N + 255) / 256, 256, 0, stream>>>(out1b, w2hi, w2lo, att_s2, att_d2, h2b, as2, ad2, N);
    k_fagg2<<<(N + 3) / 4, 256, 0, stream>>>(h2b, as2, ad2, rowstart, csr, b2, out2, N);

    // pool + linear
    k_pool<<<NG, 64, 0, stream>>>(out2, gstart, lin_w, lin_b, out, NG);
}

// Round 13
// 316.570 us; speedup vs baseline: 1.0028x; 1.0028x over previous
//
#include <hip/hip_runtime.h>

#define F_IN 128
#define HID 64
#define HEADS 4
#define NC 8

typedef __bf16 bf16_t;
typedef bf16_t bf16x8 __attribute__((ext_vector_type(8)));
typedef float f32x4 __attribute__((ext_vector_type(4)));
typedef float f32x2 __attribute__((ext_vector_type(2)));

union BF8 { bf16x8 v; ushort u[8]; };

// ---------------------------------------------------------------- helpers

__device__ __forceinline__ ushort f2bf(float f) {      // RNE round to bf16
    uint u = __float_as_uint(f);
    return (ushort)((u + 0x7fffu + ((u >> 16) & 1u)) >> 16);
}
__device__ __forceinline__ float bf2f(ushort h) {
    return __uint_as_float(((uint)h) << 16);
}
__device__ __forceinline__ float edgew(float e) {      // exp(leaky_relu(e, 0.2))
    e = (e > 0.f) ? e : 0.2f * e;
    return __expf(e);
}
// unpack a uint holding 2 bf16 (lo=ch2p, hi=ch2p+1) into float2
__device__ __forceinline__ f32x2 unpk(uint u) {
    f32x2 r;
    r.x = __uint_as_float(u << 16);
    r.y = __uint_as_float(u & 0xffff0000u);
    return r;
}

// ---------------------------------------------------------------- setup
// w1p pack (for postgemm, hi only): [h(4)][ct(4)][kc(4)][lane(64)][j(8)]
// w2 pack (hi only): [ct(4)][kc(8)][lane(64)][j(8)]
// ps/pd[h][k] = sum_c W1[k][h*64+c] * att{s,d}1[h][c]
__global__ void k_setup(const float* __restrict__ W1, const float* __restrict__ W2,
                        const float* __restrict__ atts1, const float* __restrict__ attd1,
                        ushort* __restrict__ w1p, ushort* __restrict__ w2hi,
                        float* __restrict__ ps, float* __restrict__ pd,
                        int* __restrict__ deg, int N, int* __restrict__ counts, int NG) {
    int i = blockIdx.x * blockDim.x + threadIdx.x;
    if (i < N) deg[i] = 1;              // self loop contributes 1
    if (i < NG) counts[i] = 0;
    if (i < 128 * 256) {
        int k = i >> 8, n = i & 255;
        int h = n >> 6, c = n & 63;
        int ct = c >> 4, lc = c & 15, kc = k >> 5, ls = (k >> 3) & 3, j = k & 7;
        size_t off = ((((size_t)h * 4 + ct) * 4 + kc) * 64 + (ls * 16 + lc)) * 8 + j;
        w1p[off] = f2bf(W1[i]);
    }
    if (i < 256 * 64) {
        int k = i >> 6, n = i & 63;
        int ct = n >> 4, c = n & 15, kc = k >> 5, ls = (k >> 3) & 3, j = k & 7;
        size_t off = (((size_t)ct * 8 + kc) * 64 + (ls * 16 + c)) * 8 + j;
        w2hi[off] = f2bf(W2[i]);
    }
    if (i < 512) {                      // i = h*128 + k
        int h = i >> 7, k = i & 127;
        float s = 0.f, d = 0.f;
        for (int c = 0; c < 64; c++) {
            float w = W1[k * 256 + h * 64 + c];
            s += w * atts1[h * 64 + c];
            d += w * attd1[h * 64 + c];
        }
        ps[i] = s; pd[i] = d;
    }
}

// fused: edge degree count + batch count
__global__ void k_count(const int* __restrict__ ei, int E, int* __restrict__ deg,
                        const int* __restrict__ batch, int N, int* __restrict__ counts) {
    int i = blockIdx.x * blockDim.x + threadIdx.x;
    if (i < E) atomicAdd(&deg[ei[E + i]], 1);   // dst row
    if (i < N) atomicAdd(&counts[batch[i]], 1);
}

__global__ __launch_bounds__(1024) void k_scan_part(const int* __restrict__ v,
                                                    int* __restrict__ excl,
                                                    int* __restrict__ bsum, int n) {
    __shared__ int buf[1024];
    int tid = threadIdx.x;
    int i = blockIdx.x * 1024 + tid;
    int val = (i < n) ? v[i] : 0;
    buf[tid] = val;
    __syncthreads();
    for (int off = 1; off < 1024; off <<= 1) {
        int t = (tid >= off) ? buf[tid - off] : 0;
        __syncthreads();
        buf[tid] += t;
        __syncthreads();
    }
    if (i < n) excl[i] = buf[tid] - val;
    if (tid == 1023) bsum[blockIdx.x] = buf[1023];
}

// block 0: scan bsum[nb] -> boff; block 1: scan counts[ng] -> gstart[0..ng]
__global__ __launch_bounds__(1024) void k_scan_small2(const int* __restrict__ bsum,
                                                      int* __restrict__ boff, int nb,
                                                      int* __restrict__ total_out,
                                                      const int* __restrict__ counts,
                                                      int* __restrict__ gstart, int ng) {
    __shared__ int buf[1024];
    int tid = threadIdx.x;
    const int* src = (blockIdx.x == 0) ? bsum : counts;
    int cnt = (blockIdx.x == 0) ? nb : ng;
    int val = (tid < cnt) ? src[tid] : 0;
    buf[tid] = val;
    __syncthreads();
    for (int off = 1; off < 1024; off <<= 1) {
        int t = (tid >= off) ? buf[tid - off] : 0;
        __syncthreads();
        buf[tid] += t;
        __syncthreads();
    }
    if (blockIdx.x == 0) {
        if (tid < cnt) boff[tid] = buf[tid] - val;
        if (tid == 1023) total_out[0] = buf[1023];
    } else {
        if (tid < cnt) gstart[tid] = buf[tid] - val;
        if (tid == 1023) gstart[ng] = buf[1023];
    }
}

__global__ void k_scan_add_self(int* __restrict__ rowstart, const int* __restrict__ boff,
                                int* __restrict__ cursor, int* __restrict__ csr, int n) {
    int i = blockIdx.x * blockDim.x + threadIdx.x;
    if (i < n) {
        int rs = rowstart[i] + boff[i >> 10];
        rowstart[i] = rs;
        csr[rs] = i;          // self loop first
        cursor[i] = 1;
    }
}

__global__ void k_scatter(const int* __restrict__ ei, int E, const int* __restrict__ rowstart,
                          int* __restrict__ cursor, int* __restrict__ csr) {
    int e = blockIdx.x * blockDim.x + threadIdx.x;
    if (e < E) {
        int d = ei[E + e], s = ei[e];
        int pos = atomicAdd(&cursor[d], 1);
        csr[rowstart[d] + pos] = s;
    }
}

// ---------------------------------------------------------------- proj: xb = bf16(x); as1/ad1 = x . ps/pd
__global__ __launch_bounds__(256) void k_proj(const float* __restrict__ x,
                                              const float* __restrict__ ps,
                                              const float* __restrict__ pd,
                                              ushort* __restrict__ xb,
                                              float* __restrict__ as1, float* __restrict__ ad1,
                                              int N) {
    __shared__ float lps[512], lpd[512];
    int tid = threadIdx.x;
    lps[tid] = ps[tid]; lps[tid + 256] = ps[tid + 256];
    lpd[tid] = pd[tid]; lpd[tid + 256] = pd[tid + 256];
    __syncthreads();
    int wid = tid >> 6, lane = tid & 63;
    int n = blockIdx.x * 4 + wid;
    if (n >= N) return;
    float2 xv = *(const float2*)(x + (size_t)n * 128 + lane * 2);
    ushort2 xbv; xbv.x = f2bf(xv.x); xbv.y = f2bf(xv.y);
    *(ushort2*)(xb + (size_t)n * 128 + lane * 2) = xbv;
    float s[4], d[4];
    #pragma unroll
    for (int h = 0; h < 4; h++) {
        s[h] = xv.x * lps[h * 128 + 2 * lane] + xv.y * lps[h * 128 + 2 * lane + 1];
        d[h] = xv.x * lpd[h * 128 + 2 * lane] + xv.y * lpd[h * 128 + 2 * lane + 1];
    }
    #pragma unroll
    for (int off = 1; off < 64; off <<= 1) {
        #pragma unroll
        for (int h = 0; h < 4; h++) {
            s[h] += __shfl_xor(s[h], off);
            d[h] += __shfl_xor(d[h], off);
        }
    }
    if (lane == 0) {
        float4 sv = {s[0], s[1], s[2], s[3]};
        float4 dv = {d[0], d[1], d[2], d[3]};
        *(float4*)(as1 + (size_t)n * 4) = sv;
        *(float4*)(ad1 + (size_t)n * 4) = dv;
    }
}

// ---------------------------------------------------------------- fused edgew + x-space aggregation (layer 1)
// 1 wave/node. Phase A: lane-per-edge weights -> LDS. Phase B: 4 edges per load instr
// (16 lanes x 16B cover a 256B row); f32x2 packed accumulation (v_pk_fma_f32).
__global__ __launch_bounds__(256) void k_fagg1(const ushort* __restrict__ xb,
                                               const float* __restrict__ as1,
                                               const float* __restrict__ ad1,
                                               const int* __restrict__ rowstart,
                                               const int* __restrict__ csr,
                                               ushort* __restrict__ xaggb, int N) {
    __shared__ float lw[4][256];
    __shared__ int   lsrc[4][64];
    int wid = threadIdx.x >> 6, lane = threadIdx.x & 63;
    int n = blockIdx.x * 4 + wid;
    if (n >= N) return;
    int beg = rowstart[n], end = rowstart[n + 1];
    float4 adv = *(const float4*)(ad1 + (size_t)n * 4);
    int g = lane >> 4, li = lane & 15;
    int c0 = li * 8;
    float s0 = 0.f, s1 = 0.f, s2 = 0.f, s3 = 0.f;
    f32x2 a2[4][4];
    #pragma unroll
    for (int h = 0; h < 4; h++)
        #pragma unroll
        for (int p = 0; p < 4; p++) a2[h][p] = (f32x2){0.f, 0.f};

    for (int jc = beg; jc < end; jc += 64) {
        // phase A: lane-per-edge weights
        int j = jc + lane;
        float4 wv = {0.f, 0.f, 0.f, 0.f};
        int src = 0;
        if (j < end) {
            src = csr[j];
            float4 av = *(const float4*)(as1 + (size_t)src * 4);
            wv.x = edgew(av.x + adv.x); wv.y = edgew(av.y + adv.y);
            wv.z = edgew(av.z + adv.z); wv.w = edgew(av.w + adv.w);
            s0 += wv.x; s1 += wv.y; s2 += wv.z; s3 += wv.w;
        }
        *(float4*)&lw[wid][lane * 4] = wv;
        lsrc[wid][lane] = src;
        // phase B: 4 rows in flight per iteration (pad slots have w=0)
        int cnt = min(64, end - jc);
        int iters = (cnt + 3) >> 2;
        for (int t = 0; t < iters; t += 4) {
            #pragma unroll
            for (int u = 0; u < 4; u++) {
                int tt = t + u;
                if (tt < iters) {
                    int e = tt * 4 + g;
                    int sr = lsrc[wid][e];
                    float4 wv4 = *(const float4*)&lw[wid][e * 4];
                    uint4 hv = *(const uint4*)(xb + (size_t)sr * 128 + c0);
                    f32x2 v[4];
                    v[0] = unpk(hv.x); v[1] = unpk(hv.y);
                    v[2] = unpk(hv.z); v[3] = unpk(hv.w);
                    f32x2 w0 = {wv4.x, wv4.x}, w1 = {wv4.y, wv4.y};
                    f32x2 w2 = {wv4.z, wv4.z}, w3 = {wv4.w, wv4.w};
                    #pragma unroll
                    for (int p = 0; p < 4; p++) {
                        a2[0][p] += w0 * v[p];
                        a2[1][p] += w1 * v[p];
                        a2[2][p] += w2 * v[p];
                        a2[3][p] += w3 * v[p];
                    }
                }
            }
        }
    }
    // cross-group reduce (groups hold disjoint edge subsets)
    #pragma unroll
    for (int h = 0; h < 4; h++)
        #pragma unroll
        for (int p = 0; p < 4; p++) {
            a2[h][p].x += __shfl_xor(a2[h][p].x, 16);
            a2[h][p].x += __shfl_xor(a2[h][p].x, 32);
            a2[h][p].y += __shfl_xor(a2[h][p].y, 16);
            a2[h][p].y += __shfl_xor(a2[h][p].y, 32);
        }
    // softmax denominators
    #pragma unroll
    for (int off = 1; off < 64; off <<= 1) {
        s0 += __shfl_xor(s0, off); s1 += __shfl_xor(s1, off);
        s2 += __shfl_xor(s2, off); s3 += __shfl_xor(s3, off);
    }
    if (g == 0) {
        float inv[4] = {1.f / s0, 1.f / s1, 1.f / s2, 1.f / s3};
        #pragma unroll
        for (int h = 0; h < 4; h++) {
            uint4 ov;
            ov.x = (uint)f2bf(a2[h][0].x * inv[h]) | ((uint)f2bf(a2[h][0].y * inv[h]) << 16);
            ov.y = (uint)f2bf(a2[h][1].x * inv[h]) | ((uint)f2bf(a2[h][1].y * inv[h]) << 16);
            ov.z = (uint)f2bf(a2[h][2].x * inv[h]) | ((uint)f2bf(a2[h][2].y * inv[h]) << 16);
            ov.w = (uint)f2bf(a2[h][3].x * inv[h]) | ((uint)f2bf(a2[h][3].y * inv[h]) << 16);
            *(uint4*)(xaggb + ((size_t)h * N + n) * 128 + c0) = ov;
        }
    }
}

// ---------------------------------------------------------------- postgemm: out1 = relu(xagg[h] @ W1[:,h] + b1)
__global__ __launch_bounds__(256) void k_postgemm(const ushort* __restrict__ xaggb,
                                                  const ushort* __restrict__ w1p,
                                                  const float* __restrict__ b1,
                                                  ushort* __restrict__ out1b, int N) {
    __shared__ __align__(16) ushort lw[8192];   // 16 KB: this head's W pack
    int tid = threadIdx.x;
    int h = blockIdx.y;
    {
        float4* dh = (float4*)lw; const float4* sh = (const float4*)(w1p + (size_t)h * 8192);
        #pragma unroll
        for (int i = 0; i < 4; i++) dh[tid + i * 256] = sh[tid + i * 256];
    }
    __syncthreads();
    int w = tid >> 6, l = tid & 63;
    int lc = l & 15, lk = l >> 4;
    int rbase = blockIdx.x * 256 + w * 64;
    const ushort* abase = xaggb + (size_t)h * N * 128;

    f32x4 acc[4][4];
    #pragma unroll
    for (int mt = 0; mt < 4; mt++)
        #pragma unroll
        for (int ct = 0; ct < 4; ct++) acc[mt][ct] = (f32x4){0.f, 0.f, 0.f, 0.f};

    #pragma unroll
    for (int kc = 0; kc < 4; kc++) {
        BF8 a[4];
        #pragma unroll
        for (int mt = 0; mt < 4; mt++) {
            int row = rbase + mt * 16 + lc;
            if (row < N) {
                a[mt].v = *(const bf16x8*)(abase + (size_t)row * 128 + kc * 32 + lk * 8);
            } else {
                #pragma unroll
                for (int j = 0; j < 8; j++) a[mt].u[j] = 0;
            }
        }
        #pragma unroll
        for (int ct = 0; ct < 4; ct++) {
            bf16x8 bv = *(const bf16x8*)(lw + ((ct * 4 + kc) * 64 + l) * 8);
            #pragma unroll
            for (int mt = 0; mt < 4; mt++) {
                acc[mt][ct] = __builtin_amdgcn_mfma_f32_16x16x32_bf16(a[mt].v, bv, acc[mt][ct], 0, 0, 0);
            }
        }
    }
    #pragma unroll
    for (int mt = 0; mt < 4; mt++) {
        int rowb = rbase + mt * 16 + lk * 4;
        #pragma unroll
        for (int ct = 0; ct < 4; ct++) {
            int col = h * 64 + ct * 16 + lc;
            float bb = b1[col];
            #pragma unroll
            for (int r = 0; r < 4; r++) {
                int row = rowb + r;
                if (row < N) {
                    float o = acc[mt][ct][r] + bb;
                    out1b[(size_t)row * 256 + col] = f2bf(o > 0.f ? o : 0.f);
                }
            }
        }
    }
}

// ---------------------------------------------------------------- layer-2 GEMM (MFMA, W2hi only) + fused att
__global__ __launch_bounds__(256) void k_gemm2(const ushort* __restrict__ xin,
                                               const ushort* __restrict__ w2hi,
                                               const float* __restrict__ atts,
                                               const float* __restrict__ attd,
                                               ushort* __restrict__ h2b,
                                               float* __restrict__ as2, float* __restrict__ ad2,
                                               int N) {
    __shared__ __align__(16) ushort lhi[16384];
    int tid = threadIdx.x;
    {
        float4* dh = (float4*)lhi; const float4* sh = (const float4*)w2hi;
        #pragma unroll
        for (int i = 0; i < 8; i++) dh[tid + i * 256] = sh[tid + i * 256];
    }
    __syncthreads();
    int w = tid >> 6, l = tid & 63;
    int lc = l & 15, lk = l >> 4;
    int rbase = blockIdx.x * 256 + w * 64;

    f32x4 acc[4][4];
    #pragma unroll
    for (int mt = 0; mt < 4; mt++)
        #pragma unroll
        for (int ct = 0; ct < 4; ct++) acc[mt][ct] = (f32x4){0.f, 0.f, 0.f, 0.f};

    #pragma unroll
    for (int kc = 0; kc < 8; kc++) {
        BF8 a[4];
        #pragma unroll
        for (int mt = 0; mt < 4; mt++) {
            int row = rbase + mt * 16 + lc;
            if (row < N) {
                a[mt].v = *(const bf16x8*)(xin + (size_t)row * 256 + kc * 32 + lk * 8);
            } else {
                #pragma unroll
                for (int j = 0; j < 8; j++) a[mt].u[j] = 0;
            }
        }
        #pragma unroll
        for (int ct = 0; ct < 4; ct++) {
            bf16x8 bhi = *(const bf16x8*)(lhi + ((ct * 8 + kc) * 64 + l) * 8);
            #pragma unroll
            for (int mt = 0; mt < 4; mt++) {
                acc[mt][ct] = __builtin_amdgcn_mfma_f32_16x16x32_bf16(a[mt].v, bhi, acc[mt][ct], 0, 0, 0);
            }
        }
    }
    #pragma unroll
    for (int mt = 0; mt < 4; mt++) {
        int rowb = rbase + mt * 16 + lk * 4;
        #pragma unroll
        for (int ct = 0; ct < 4; ct++) {
            int col = ct * 16 + lc;
            #pragma unroll
            for (int r = 0; r < 4; r++) {
                int row = rowb + r;
                if (row < N) h2b[(size_t)row * 64 + col] = f2bf(acc[mt][ct][r]);
            }
        }
        float s[4] = {0.f, 0.f, 0.f, 0.f}, d[4] = {0.f, 0.f, 0.f, 0.f};
        #pragma unroll
        for (int ct = 0; ct < 4; ct++) {
            int col = ct * 16 + lc;
            float av = atts[col], dv = attd[col];
            #pragma unroll
            for (int r = 0; r < 4; r++) { s[r] += acc[mt][ct][r] * av; d[r] += acc[mt][ct][r] * dv; }
        }
        #pragma unroll
        for (int r = 0; r < 4; r++) {
            #pragma unroll
            for (int off = 1; off < 16; off <<= 1) {
                s[r] += __shfl_xor(s[r], off);
                d[r] += __shfl_xor(d[r], off);
            }
        }
        if (lc == 0) {
            #pragma unroll
            for (int r = 0; r < 4; r++) {
                int row = rowb + r;
                if (row < N) { as2[row] = s[r]; ad2[row] = d[r]; }
            }
        }
    }
}

// ---------------------------------------------------------------- fused edgew + aggregation, layer 2 (pk-fma)
__global__ __launch_bounds__(256) void k_fagg2(const ushort* __restrict__ h2b,
                                               const float* __restrict__ as2,
                                               const float* __restrict__ ad2,
                                               const int* __restrict__ rowstart,
                                               const int* __restrict__ csr,
                                               const float* __restrict__ b2,
                                               float* __restrict__ out2, int N) {
    __shared__ float lw[4][64];
    __shared__ int   lsrc[4][64];
    int wid = threadIdx.x >> 6, lane = threadIdx.x & 63;
    int n = blockIdx.x * 4 + wid;
    if (n >= N) return;
    int beg = rowstart[n], end = rowstart[n + 1];
    float adv = ad2[n];
    int g = lane >> 3, li = lane & 7;
    int c0 = li * 8;
    float ss = 0.f;
    f32x2 a2[4];
    #pragma unroll
    for (int i = 0; i < 4; i++) a2[i] = (f32x2){0.f, 0.f};

    for (int jc = beg; jc < end; jc += 64) {
        int j = jc + lane;
        float wgt = 0.f;
        int src = 0;
        if (j < end) {
            src = csr[j];
            wgt = edgew(as2[src] + adv);
            ss += wgt;
        }
        lw[wid][lane] = wgt;
        lsrc[wid][lane] = src;
        int cnt = min(64, end - jc);
        int groups = (cnt + 7) >> 3;
        for (int t = 0; t < groups; t += 2) {
            #pragma unroll
            for (int u = 0; u < 2; u++) {
                int tt = t + u;
                if (tt < groups) {
                    int e = tt * 8 + g;
                    int sr = lsrc[wid][e];
                    float wv = lw[wid][e];
                    uint4 hv = *(const uint4*)(h2b + (size_t)sr * 64 + c0);
                    f32x2 ws = {wv, wv};
                    a2[0] += ws * unpk(hv.x);
                    a2[1] += ws * unpk(hv.y);
                    a2[2] += ws * unpk(hv.z);
                    a2[3] += ws * unpk(hv.w);
                }
            }
        }
    }
    // reduce across 8 edge-groups
    #pragma unroll
    for (int i = 0; i < 4; i++) {
        a2[i].x += __shfl_xor(a2[i].x, 8);
        a2[i].x += __shfl_xor(a2[i].x, 16);
        a2[i].x += __shfl_xor(a2[i].x, 32);
        a2[i].y += __shfl_xor(a2[i].y, 8);
        a2[i].y += __shfl_xor(a2[i].y, 16);
        a2[i].y += __shfl_xor(a2[i].y, 32);
    }
    #pragma unroll
    for (int off = 1; off < 64; off <<= 1) ss += __shfl_xor(ss, off);
    float inv = 1.f / ss;
    if (g == 0) {
        const float4* bv = (const float4*)(b2 + c0);
        float4 bA = bv[0], bB = bv[1];
        float4 oA, oB;
        oA.x = fmaxf(a2[0].x * inv + bA.x, 0.f); oA.y = fmaxf(a2[0].y * inv + bA.y, 0.f);
        oA.z = fmaxf(a2[1].x * inv + bA.z, 0.f); oA.w = fmaxf(a2[1].y * inv + bA.w, 0.f);
        oB.x = fmaxf(a2[2].x * inv + bB.x, 0.f); oB.y = fmaxf(a2[2].y * inv + bB.y, 0.f);
        oB.z = fmaxf(a2[3].x * inv + bB.z, 0.f); oB.w = fmaxf(a2[3].y * inv + bB.w, 0.f);
        float* op = out2 + (size_t)n * 64 + c0;
        *(float4*)op = oA;
        *(float4*)(op + 4) = oB;
    }
}

// ---------------------------------------------------------------- pool + final linear

__global__ __launch_bounds__(64) void k_pool(const float* __restrict__ out2,
                                             const int* __restrict__ gstart,
                                             const float* __restrict__ lin_w,
                                             const float* __restrict__ lin_b,
                                             float* __restrict__ out, int NG) {
    __shared__ float mean[64];
    int g = blockIdx.x;
    int lane = threadIdx.x;
    int beg = gstart[g], end = gstart[g + 1];
    float s = 0.f;
    for (int n = beg; n < end; n++) s += out2[(size_t)n * 64 + lane];
    float cnt = (float)(end - beg);
    mean[lane] = s / fmaxf(cnt, 1.f);
    __syncthreads();
    if (lane < NC) {
        float acc = lin_b[lane];
        #pragma unroll
        for (int c = 0; c < 64; c++) acc += mean[c] * lin_w[c * NC + lane];
        out[g * NC + lane] = acc;
    }
}

// ---------------------------------------------------------------- launch

extern "C" void kernel_launch(void* const* d_in, const int* in_sizes, int n_in,
                              void* d_out, int out_size, void* d_ws, size_t ws_size,
                              hipStream_t stream) {
    const float* x      = (const float*)d_in[0];
    const int*   ei     = (const int*)d_in[1];
    const int*   batch  = (const int*)d_in[2];
    const float* W1     = (const float*)d_in[3];
    const float* att_s1 = (const float*)d_in[4];
    const float* att_d1 = (const float*)d_in[5];
    const float* b1     = (const float*)d_in[6];
    const float* W2     = (const float*)d_in[7];
    const float* att_s2 = (const float*)d_in[8];
    const float* att_d2 = (const float*)d_in[9];
    const float* b2     = (const float*)d_in[10];
    const float* lin_w  = (const float*)d_in[11];
    const float* lin_b  = (const float*)d_in[12];
    float* out = (float*)d_out;

    const int N  = in_sizes[0] / F_IN;   // 50000
    const int E  = in_sizes[1] / 2;      // 800000
    const int NG = out_size / NC;        // 512
    const int NE = E + N;
    const int NB = (N + 1023) / 1024;    // scan blocks

    char* p = (char*)d_ws;
    auto alloc = [&](size_t bytes) { char* r = p; p += (bytes + 255) & ~(size_t)255; return r; };
    ushort* xb      = (ushort*)alloc(sizeof(ushort) * (size_t)N * 128);   // out2 aliases later
    ushort* xaggb   = (ushort*)alloc(sizeof(ushort) * (size_t)N * 512);   // [h][n][128]
    ushort* out1b   = (ushort*)alloc(sizeof(ushort) * (size_t)N * 256);
    ushort* h2b     = (ushort*)alloc(sizeof(ushort) * (size_t)N * 64);
    float*  as1     = (float*)alloc(sizeof(float) * (size_t)N * 4);
    float*  ad1     = (float*)alloc(sizeof(float) * (size_t)N * 4);
    float*  as2     = (float*)alloc(sizeof(float) * (size_t)N);
    float*  ad2     = (float*)alloc(sizeof(float) * (size_t)N);
    int*    rowstart= (int*)alloc(sizeof(int) * (size_t)(N + 1));
    int*    itmp    = (int*)alloc(sizeof(int) * (size_t)N);      // deg, then cursor
    int*    csr     = (int*)alloc(sizeof(int) * (size_t)NE);
    int*    counts  = (int*)alloc(sizeof(int) * (size_t)NG);
    int*    gstart  = (int*)alloc(sizeof(int) * (size_t)(NG + 1));
    int*    bsum    = (int*)alloc(sizeof(int) * 1024);
    int*    boff    = (int*)alloc(sizeof(int) * 1024);
    ushort* w1p     = (ushort*)alloc(sizeof(ushort) * 32768);
    ushort* w2hi    = (ushort*)alloc(sizeof(ushort) * 16384);
    float*  psv     = (float*)alloc(sizeof(float) * 512);
    float*  pdv     = (float*)alloc(sizeof(float) * 512);
    float*  out2    = (float*)xb;    // alias: xb dead after k_fagg1

    int bs = 256;
    k_setup<<<(N + bs - 1) / bs, bs, 0, stream>>>(W1, W2, att_s1, att_d1, w1p, w2hi,
                                                  psv, pdv, itmp, N, counts, NG);
    k_count<<<(E + bs - 1) / bs, bs, 0, stream>>>(ei, E, itmp, batch, N, counts);
    k_scan_part<<<NB, 1024, 0, stream>>>(itmp, rowstart, bsum, N);
    k_scan_small2<<<2, 1024, 0, stream>>>(bsum, boff, NB, rowstart + N, counts, gstart, NG);
    k_scan_add_self<<<(N + 1023) / 1024, 1024, 0, stream>>>(rowstart, boff, itmp, csr, N);
    k_scatter<<<(E + bs - 1) / bs, bs, 0, stream>>>(ei, E, rowstart, itmp, csr);

    // layer 1: proj -> x-space aggregation -> post-GEMM
    k_proj<<<(N + 3) / 4, 256, 0, stream>>>(x, psv, pdv, xb, as1, ad1, N);
    k_fagg1<<<(N + 3) / 4, 256, 0, stream>>>(xb, as1, ad1, rowstart, csr, xaggb, N);
    k_postgemm<<<dim3((N + 255) / 256, 4), 256, 0, stream>>>(xaggb, w1p, b1, out1b, N);

    // layer 2
    k_gemm2<<<(N + 255) / 256, 256, 0, stream>>>(out1b, w2hi, att_s2, att_d2, h2b, as2, ad2, N);
    k_fagg2<<<(N + 3) / 4, 256, 0, stream>>>(h2b, as2, ad2, rowstart, csr, b2, out2, N);

    // pool + linear
    k_pool<<<NG, 64, 0, stream>>>(out2, gstart, lin_w, lin_b, out, NG);
}

// Round 14
// 300.434 us; speedup vs baseline: 1.0567x; 1.0537x over previous
//
#include <hip/hip_runtime.h>

#define F_IN 128
#define HID 64
#define HEADS 4
#define NC 8

typedef __bf16 bf16_t;
typedef bf16_t bf16x8 __attribute__((ext_vector_type(8)));
typedef float f32x4 __attribute__((ext_vector_type(4)));
typedef float f32x2 __attribute__((ext_vector_type(2)));

union BF8 { bf16x8 v; ushort u[8]; };

// ---------------------------------------------------------------- helpers

__device__ __forceinline__ ushort f2bf(float f) {      // RNE round to bf16
    uint u = __float_as_uint(f);
    return (ushort)((u + 0x7fffu + ((u >> 16) & 1u)) >> 16);
}
__device__ __forceinline__ float bf2f(ushort h) {
    return __uint_as_float(((uint)h) << 16);
}
__device__ __forceinline__ float edgew(float e) {      // exp(leaky_relu(e, 0.2))
    e = (e > 0.f) ? e : 0.2f * e;
    return __expf(e);
}
// unpack a uint holding 2 bf16 (lo, hi) into float2
__device__ __forceinline__ f32x2 unpk(uint u) {
    f32x2 r;
    r.x = __uint_as_float(u << 16);
    r.y = __uint_as_float(u & 0xffff0000u);
    return r;
}

// ---------------------------------------------------------------- setup: W pack + deg/count init
// W1 pack (hi only): [cy(2)][ct(8)][kc(4)][lane(64)][j(8)]
// W2 pack (hi only): [ct(4)][kc(8)][lane(64)][j(8)]
__global__ void k_setup(const float* __restrict__ W1, const float* __restrict__ W2,
                        ushort* __restrict__ w1hi, ushort* __restrict__ w2hi,
                        int* __restrict__ deg, int N, int* __restrict__ counts, int NG) {
    int i = blockIdx.x * blockDim.x + threadIdx.x;
    if (i < N) deg[i] = 1;              // self loop contributes 1
    if (i < NG) counts[i] = 0;
    if (i < 128 * 256) {
        int k = i >> 8, n = i & 255;
        int cy = n >> 7, ct = (n >> 4) & 7, c = n & 15, kc = k >> 5, ls = (k >> 3) & 3, j = k & 7;
        size_t off = ((((size_t)cy * 8 + ct) * 4 + kc) * 64 + (ls * 16 + c)) * 8 + j;
        w1hi[off] = f2bf(W1[i]);
    }
    if (i < 256 * 64) {
        int k = i >> 6, n = i & 63;
        int ct = n >> 4, c = n & 15, kc = k >> 5, ls = (k >> 3) & 3, j = k & 7;
        size_t off = (((size_t)ct * 8 + kc) * 64 + (ls * 16 + c)) * 8 + j;
        w2hi[off] = f2bf(W2[i]);
    }
}

// fused: edge degree count + batch count
__global__ void k_count(const int* __restrict__ ei, int E, int* __restrict__ deg,
                        const int* __restrict__ batch, int N, int* __restrict__ counts) {
    int i = blockIdx.x * blockDim.x + threadIdx.x;
    if (i < E) atomicAdd(&deg[ei[E + i]], 1);   // dst row
    if (i < N) atomicAdd(&counts[batch[i]], 1);
}

__global__ __launch_bounds__(1024) void k_scan_part(const int* __restrict__ v,
                                                    int* __restrict__ excl,
                                                    int* __restrict__ bsum, int n) {
    __shared__ int buf[1024];
    int tid = threadIdx.x;
    int i = blockIdx.x * 1024 + tid;
    int val = (i < n) ? v[i] : 0;
    buf[tid] = val;
    __syncthreads();
    for (int off = 1; off < 1024; off <<= 1) {
        int t = (tid >= off) ? buf[tid - off] : 0;
        __syncthreads();
        buf[tid] += t;
        __syncthreads();
    }
    if (i < n) excl[i] = buf[tid] - val;
    if (tid == 1023) bsum[blockIdx.x] = buf[1023];
}

// block 0: scan bsum[nb] -> boff; block 1: scan counts[ng] -> gstart[0..ng]
__global__ __launch_bounds__(1024) void k_scan_small2(const int* __restrict__ bsum,
                                                      int* __restrict__ boff, int nb,
                                                      int* __restrict__ total_out,
                                                      const int* __restrict__ counts,
                                                      int* __restrict__ gstart, int ng) {
    __shared__ int buf[1024];
    int tid = threadIdx.x;
    const int* src = (blockIdx.x == 0) ? bsum : counts;
    int cnt = (blockIdx.x == 0) ? nb : ng;
    int val = (tid < cnt) ? src[tid] : 0;
    buf[tid] = val;
    __syncthreads();
    for (int off = 1; off < 1024; off <<= 1) {
        int t = (tid >= off) ? buf[tid - off] : 0;
        __syncthreads();
        buf[tid] += t;
        __syncthreads();
    }
    if (blockIdx.x == 0) {
        if (tid < cnt) boff[tid] = buf[tid] - val;
        if (tid == 1023) total_out[0] = buf[1023];
    } else {
        if (tid < cnt) gstart[tid] = buf[tid] - val;
        if (tid == 1023) gstart[ng] = buf[1023];
    }
}

__global__ void k_scan_add_self(int* __restrict__ rowstart, const int* __restrict__ boff,
                                int* __restrict__ cursor, int* __restrict__ csr, int n) {
    int i = blockIdx.x * blockDim.x + threadIdx.x;
    if (i < n) {
        int rs = rowstart[i] + boff[i >> 10];
        rowstart[i] = rs;
        csr[rs] = i;          // self loop first
        cursor[i] = 1;
    }
}

__global__ void k_scatter(const int* __restrict__ ei, int E, const int* __restrict__ rowstart,
                          int* __restrict__ cursor, int* __restrict__ csr) {
    int e = blockIdx.x * blockDim.x + threadIdx.x;
    if (e < E) {
        int d = ei[E + e], s = ei[e];
        int pos = atomicAdd(&cursor[d], 1);
        csr[rowstart[d] + pos] = s;
    }
}

// ---------------------------------------------------------------- layer-1 GEMM (MFMA) + fused att
// h1 = bf16(x) @ W1hi (1 MFMA per tile)
__global__ __launch_bounds__(256) void k_gemm1(const float* __restrict__ x,
                                               const ushort* __restrict__ w1hi,
                                               const float* __restrict__ atts,
                                               const float* __restrict__ attd,
                                               ushort* __restrict__ h1b,
                                               float* __restrict__ as1, float* __restrict__ ad1,
                                               int N) {
    __shared__ __align__(16) ushort lhi[16384];   // 32 KB
    int tid = threadIdx.x;
    int cy = blockIdx.y;
    {   // stage this col-half's W pack slice
        float4* dh = (float4*)lhi; const float4* sh = (const float4*)(w1hi + (size_t)cy * 16384);
        #pragma unroll
        for (int i = 0; i < 8; i++) dh[tid + i * 256] = sh[tid + i * 256];
    }
    __syncthreads();
    int w = tid >> 6, l = tid & 63;
    int lc = l & 15, lk = l >> 4;
    int rbase = blockIdx.x * 256 + w * 64;

    f32x4 acc[4][8];
    #pragma unroll
    for (int mt = 0; mt < 4; mt++)
        #pragma unroll
        for (int ct = 0; ct < 8; ct++) acc[mt][ct] = (f32x4){0.f, 0.f, 0.f, 0.f};

    #pragma unroll
    for (int kc = 0; kc < 4; kc++) {
        BF8 ahi[4];
        #pragma unroll
        for (int mt = 0; mt < 4; mt++) {
            int row = rbase + mt * 16 + lc;
            float4 v0 = {0.f, 0.f, 0.f, 0.f}, v1 = v0;
            if (row < N) {
                const float* xp = x + (size_t)row * F_IN + kc * 32 + lk * 8;
                v0 = *(const float4*)xp; v1 = *(const float4*)(xp + 4);
            }
            float vals[8] = {v0.x, v0.y, v0.z, v0.w, v1.x, v1.y, v1.z, v1.w};
            #pragma unroll
            for (int j = 0; j < 8; j++) ahi[mt].u[j] = f2bf(vals[j]);
        }
        #pragma unroll
        for (int ct = 0; ct < 8; ct++) {
            int boff = ((ct * 4 + kc) * 64 + l) * 8;
            bf16x8 bhi = *(const bf16x8*)(lhi + boff);
            #pragma unroll
            for (int mt = 0; mt < 4; mt++) {
                acc[mt][ct] = __builtin_amdgcn_mfma_f32_16x16x32_bf16(ahi[mt].v, bhi, acc[mt][ct], 0, 0, 0);
            }
        }
    }
    // epilogue: C/D layout col=lane&15, row=(lane>>4)*4+reg
    #pragma unroll
    for (int mt = 0; mt < 4; mt++) {
        int rowb = rbase + mt * 16 + lk * 4;
        #pragma unroll
        for (int ct = 0; ct < 8; ct++) {
            int col = cy * 128 + ct * 16 + lc;
            #pragma unroll
            for (int r = 0; r < 4; r++) {
                int row = rowb + r;
                if (row < N) h1b[(size_t)row * 256 + col] = f2bf(acc[mt][ct][r]);
            }
        }
        #pragma unroll
        for (int hh = 0; hh < 2; hh++) {
            float s[4] = {0.f, 0.f, 0.f, 0.f}, d[4] = {0.f, 0.f, 0.f, 0.f};
            #pragma unroll
            for (int cq = 0; cq < 4; cq++) {
                int ct = hh * 4 + cq;
                int col = cy * 128 + ct * 16 + lc;
                float av = atts[col], dv = attd[col];
                #pragma unroll
                for (int r = 0; r < 4; r++) { s[r] += acc[mt][ct][r] * av; d[r] += acc[mt][ct][r] * dv; }
            }
            #pragma unroll
            for (int r = 0; r < 4; r++) {
                #pragma unroll
                for (int off = 1; off < 16; off <<= 1) {
                    s[r] += __shfl_xor(s[r], off);
                    d[r] += __shfl_xor(d[r], off);
                }
            }
            if (lc == 0) {
                int head = cy * 2 + hh;
                #pragma unroll
                for (int r = 0; r < 4; r++) {
                    int row = rowb + r;
                    if (row < N) { as1[row * 4 + head] = s[r]; ad1[row * 4 + head] = d[r]; }
                }
            }
        }
    }
}

// ---------------------------------------------------------------- fused edgew + aggregation, layer 1
// 1 wave/node, h-space. Phase A: lane-per-edge weight -> LDS. Phase B: 2 rows per load instr
// (32 lanes x 16B cover a 512B row), unroll 8, f32x2 packed accumulation.
__global__ __launch_bounds__(256) void k_fagg1(const ushort* __restrict__ h1b,
                                               const float* __restrict__ as1,
                                               const float* __restrict__ ad1,
                                               const int* __restrict__ rowstart,
                                               const int* __restrict__ csr,
                                               const float* __restrict__ b1,
                                               ushort* __restrict__ out1b, int N) {
    __shared__ float lw[4][256];
    __shared__ int   lsrc[4][64];
    int wid = threadIdx.x >> 6, lane = threadIdx.x & 63;
    int n = blockIdx.x * 4 + wid;
    if (n >= N) return;
    int beg = rowstart[n], end = rowstart[n + 1];
    float4 adv = *(const float4*)(ad1 + (size_t)n * 4);
    int lh = lane & 31, half = lane >> 5;
    int c0 = lh * 8;             // channel base (bf16 units)
    int head = lh >> 3;
    float s0 = 0.f, s1 = 0.f, s2 = 0.f, s3 = 0.f;
    f32x2 a2[4];
    #pragma unroll
    for (int i = 0; i < 4; i++) a2[i] = (f32x2){0.f, 0.f};

    for (int jc = beg; jc < end; jc += 64) {
        // phase A: lane-per-edge weights
        int j = jc + lane;
        float4 wv = {0.f, 0.f, 0.f, 0.f};
        int src = 0;
        if (j < end) {
            src = csr[j];
            float4 av = *(const float4*)(as1 + (size_t)src * 4);
            wv.x = edgew(av.x + adv.x); wv.y = edgew(av.y + adv.y);
            wv.z = edgew(av.z + adv.z); wv.w = edgew(av.w + adv.w);
            s0 += wv.x; s1 += wv.y; s2 += wv.z; s3 += wv.w;
        }
        *(float4*)&lw[wid][lane * 4] = wv;
        lsrc[wid][lane] = src;
        // phase B: paired-row aggregation (pad slots have w=0)
        int cnt = min(64, end - jc);
        int pairs = (cnt + 1) >> 1;
        for (int t = 0; t < pairs; t += 8) {
            #pragma unroll
            for (int u = 0; u < 8; u++) {
                int tt = t + u;
                if (tt < pairs) {
                    int e = 2 * tt + half;
                    int sr = lsrc[wid][e];
                    float wgt = lw[wid][e * 4 + head];
                    uint4 hv = *(const uint4*)(h1b + (size_t)sr * 256 + c0);
                    f32x2 ws = {wgt, wgt};
                    a2[0] += ws * unpk(hv.x);
                    a2[1] += ws * unpk(hv.y);
                    a2[2] += ws * unpk(hv.z);
                    a2[3] += ws * unpk(hv.w);
                }
            }
        }
    }
    // cross-half reduce (halves hold disjoint edge subsets)
    #pragma unroll
    for (int i = 0; i < 4; i++) {
        a2[i].x += __shfl_xor(a2[i].x, 32);
        a2[i].y += __shfl_xor(a2[i].y, 32);
    }
    // softmax denominators
    #pragma unroll
    for (int off = 1; off < 64; off <<= 1) {
        s0 += __shfl_xor(s0, off); s1 += __shfl_xor(s1, off);
        s2 += __shfl_xor(s2, off); s3 += __shfl_xor(s3, off);
    }
    float sv = (head == 0) ? s0 : (head == 1) ? s1 : (head == 2) ? s2 : s3;
    float inv = 1.f / sv;
    if (half == 0) {
        const float4* bv = (const float4*)(b1 + c0);
        float4 bA = bv[0], bB = bv[1];
        float o0 = fmaxf(a2[0].x * inv + bA.x, 0.f), o1 = fmaxf(a2[0].y * inv + bA.y, 0.f);
        float o2 = fmaxf(a2[1].x * inv + bA.z, 0.f), o3 = fmaxf(a2[1].y * inv + bA.w, 0.f);
        float o4 = fmaxf(a2[2].x * inv + bB.x, 0.f), o5 = fmaxf(a2[2].y * inv + bB.y, 0.f);
        float o6 = fmaxf(a2[3].x * inv + bB.z, 0.f), o7 = fmaxf(a2[3].y * inv + bB.w, 0.f);
        uint4 ov;
        ov.x = (uint)f2bf(o0) | ((uint)f2bf(o1) << 16);
        ov.y = (uint)f2bf(o2) | ((uint)f2bf(o3) << 16);
        ov.z = (uint)f2bf(o4) | ((uint)f2bf(o5) << 16);
        ov.w = (uint)f2bf(o6) | ((uint)f2bf(o7) << 16);
        *(uint4*)(out1b + (size_t)n * 256 + c0) = ov;
    }
}

// ---------------------------------------------------------------- layer-2 GEMM (MFMA, W2hi only) + fused att
__global__ __launch_bounds__(256) void k_gemm2(const ushort* __restrict__ xin,
                                               const ushort* __restrict__ w2hi,
                                               const float* __restrict__ atts,
                                               const float* __restrict__ attd,
                                               ushort* __restrict__ h2b,
                                               float* __restrict__ as2, float* __restrict__ ad2,
                                               int N) {
    __shared__ __align__(16) ushort lhi[16384];
    int tid = threadIdx.x;
    {
        float4* dh = (float4*)lhi; const float4* sh = (const float4*)w2hi;
        #pragma unroll
        for (int i = 0; i < 8; i++) dh[tid + i * 256] = sh[tid + i * 256];
    }
    __syncthreads();
    int w = tid >> 6, l = tid & 63;
    int lc = l & 15, lk = l >> 4;
    int rbase = blockIdx.x * 256 + w * 64;

    f32x4 acc[4][4];
    #pragma unroll
    for (int mt = 0; mt < 4; mt++)
        #pragma unroll
        for (int ct = 0; ct < 4; ct++) acc[mt][ct] = (f32x4){0.f, 0.f, 0.f, 0.f};

    #pragma unroll
    for (int kc = 0; kc < 8; kc++) {
        BF8 a[4];
        #pragma unroll
        for (int mt = 0; mt < 4; mt++) {
            int row = rbase + mt * 16 + lc;
            if (row < N) {
                a[mt].v = *(const bf16x8*)(xin + (size_t)row * 256 + kc * 32 + lk * 8);
            } else {
                #pragma unroll
                for (int j = 0; j < 8; j++) a[mt].u[j] = 0;
            }
        }
        #pragma unroll
        for (int ct = 0; ct < 4; ct++) {
            bf16x8 bhi = *(const bf16x8*)(lhi + ((ct * 8 + kc) * 64 + l) * 8);
            #pragma unroll
            for (int mt = 0; mt < 4; mt++) {
                acc[mt][ct] = __builtin_amdgcn_mfma_f32_16x16x32_bf16(a[mt].v, bhi, acc[mt][ct], 0, 0, 0);
            }
        }
    }
    #pragma unroll
    for (int mt = 0; mt < 4; mt++) {
        int rowb = rbase + mt * 16 + lk * 4;
        #pragma unroll
        for (int ct = 0; ct < 4; ct++) {
            int col = ct * 16 + lc;
            #pragma unroll
            for (int r = 0; r < 4; r++) {
                int row = rowb + r;
                if (row < N) h2b[(size_t)row * 64 + col] = f2bf(acc[mt][ct][r]);
            }
        }
        float s[4] = {0.f, 0.f, 0.f, 0.f}, d[4] = {0.f, 0.f, 0.f, 0.f};
        #pragma unroll
        for (int ct = 0; ct < 4; ct++) {
            int col = ct * 16 + lc;
            float av = atts[col], dv = attd[col];
            #pragma unroll
            for (int r = 0; r < 4; r++) { s[r] += acc[mt][ct][r] * av; d[r] += acc[mt][ct][r] * dv; }
        }
        #pragma unroll
        for (int r = 0; r < 4; r++) {
            #pragma unroll
            for (int off = 1; off < 16; off <<= 1) {
                s[r] += __shfl_xor(s[r], off);
                d[r] += __shfl_xor(d[r], off);
            }
        }
        if (lc == 0) {
            #pragma unroll
            for (int r = 0; r < 4; r++) {
                int row = rowb + r;
                if (row < N) { as2[row] = s[r]; ad2[row] = d[r]; }
            }
        }
    }
}

// ---------------------------------------------------------------- fused edgew + aggregation, layer 2 (pk-fma)
__global__ __launch_bounds__(256) void k_fagg2(const ushort* __restrict__ h2b,
                                               const float* __restrict__ as2,
                                               const float* __restrict__ ad2,
                                               const int* __restrict__ rowstart,
                                               const int* __restrict__ csr,
                                               const float* __restrict__ b2,
                                               float* __restrict__ out2, int N) {
    __shared__ float lw[4][64];
    __shared__ int   lsrc[4][64];
    int wid = threadIdx.x >> 6, lane = threadIdx.x & 63;
    int n = blockIdx.x * 4 + wid;
    if (n >= N) return;
    int beg = rowstart[n], end = rowstart[n + 1];
    float adv = ad2[n];
    int g = lane >> 3, li = lane & 7;
    int c0 = li * 8;
    float ss = 0.f;
    f32x2 a2[4];
    #pragma unroll
    for (int i = 0; i < 4; i++) a2[i] = (f32x2){0.f, 0.f};

    for (int jc = beg; jc < end; jc += 64) {
        int j = jc + lane;
        float wgt = 0.f;
        int src = 0;
        if (j < end) {
            src = csr[j];
            wgt = edgew(as2[src] + adv);
            ss += wgt;
        }
        lw[wid][lane] = wgt;
        lsrc[wid][lane] = src;
        int cnt = min(64, end - jc);
        int groups = (cnt + 7) >> 3;
        for (int t = 0; t < groups; t += 2) {
            #pragma unroll
            for (int u = 0; u < 2; u++) {
                int tt = t + u;
                if (tt < groups) {
                    int e = tt * 8 + g;
                    int sr = lsrc[wid][e];
                    float wv = lw[wid][e];
                    uint4 hv = *(const uint4*)(h2b + (size_t)sr * 64 + c0);
                    f32x2 ws = {wv, wv};
                    a2[0] += ws * unpk(hv.x);
                    a2[1] += ws * unpk(hv.y);
                    a2[2] += ws * unpk(hv.z);
                    a2[3] += ws * unpk(hv.w);
                }
            }
        }
    }
    // reduce across 8 edge-groups
    #pragma unroll
    for (int i = 0; i < 4; i++) {
        a2[i].x += __shfl_xor(a2[i].x, 8);
        a2[i].x += __shfl_xor(a2[i].x, 16);
        a2[i].x += __shfl_xor(a2[i].x, 32);
        a2[i].y += __shfl_xor(a2[i].y, 8);
        a2[i].y += __shfl_xor(a2[i].y, 16);
        a2[i].y += __shfl_xor(a2[i].y, 32);
    }
    #pragma unroll
    for (int off = 1; off < 64; off <<= 1) ss += __shfl_xor(ss, off);
    float inv = 1.f / ss;
    if (g == 0) {
        const float4* bv = (const float4*)(b2 + c0);
        float4 bA = bv[0], bB = bv[1];
        float4 oA, oB;
        oA.x = fmaxf(a2[0].x * inv + bA.x, 0.f); oA.y = fmaxf(a2[0].y * inv + bA.y, 0.f);
        oA.z = fmaxf(a2[1].x * inv + bA.z, 0.f); oA.w = fmaxf(a2[1].y * inv + bA.w, 0.f);
        oB.x = fmaxf(a2[2].x * inv + bB.x, 0.f); oB.y = fmaxf(a2[2].y * inv + bB.y, 0.f);
        oB.z = fmaxf(a2[3].x * inv + bB.z, 0.f); oB.w = fmaxf(a2[3].y * inv + bB.w, 0.f);
        float* op = out2 + (size_t)n * 64 + c0;
        *(float4*)op = oA;
        *(float4*)(op + 4) = oB;
    }
}

// ---------------------------------------------------------------- pool + final linear

__global__ __launch_bounds__(64) void k_pool(const float* __restrict__ out2,
                                             const int* __restrict__ gstart,
                                             const float* __restrict__ lin_w,
                                             const float* __restrict__ lin_b,
                                             float* __restrict__ out, int NG) {
    __shared__ float mean[64];
    int g = blockIdx.x;
    int lane = threadIdx.x;
    int beg = gstart[g], end = gstart[g + 1];
    float s = 0.f;
    for (int n = beg; n < end; n++) s += out2[(size_t)n * 64 + lane];
    float cnt = (float)(end - beg);
    mean[lane] = s / fmaxf(cnt, 1.f);
    __syncthreads();
    if (lane < NC) {
        float acc = lin_b[lane];
        #pragma unroll
        for (int c = 0; c < 64; c++) acc += mean[c] * lin_w[c * NC + lane];
        out[g * NC + lane] = acc;
    }
}

// ---------------------------------------------------------------- launch

extern "C" void kernel_launch(void* const* d_in, const int* in_sizes, int n_in,
                              void* d_out, int out_size, void* d_ws, size_t ws_size,
                              hipStream_t stream) {
    const float* x      = (const float*)d_in[0];
    const int*   ei     = (const int*)d_in[1];
    const int*   batch  = (const int*)d_in[2];
    const float* W1     = (const float*)d_in[3];
    const float* att_s1 = (const float*)d_in[4];
    const float* att_d1 = (const float*)d_in[5];
    const float* b1     = (const float*)d_in[6];
    const float* W2     = (const float*)d_in[7];
    const float* att_s2 = (const float*)d_in[8];
    const float* att_d2 = (const float*)d_in[9];
    const float* b2     = (const float*)d_in[10];
    const float* lin_w  = (const float*)d_in[11];
    const float* lin_b  = (const float*)d_in[12];
    float* out = (float*)d_out;

    const int N  = in_sizes[0] / F_IN;   // 50000
    const int E  = in_sizes[1] / 2;      // 800000
    const int NG = out_size / NC;        // 512
    const int NE = E + N;
    const int NB = (N + 1023) / 1024;    // scan blocks

    char* p = (char*)d_ws;
    auto alloc = [&](size_t bytes) { char* r = p; p += (bytes + 255) & ~(size_t)255; return r; };
    ushort* h1b     = (ushort*)alloc(sizeof(ushort) * (size_t)N * 256);
    ushort* out1b   = (ushort*)alloc(sizeof(ushort) * (size_t)N * 256);
    ushort* h2b     = (ushort*)alloc(sizeof(ushort) * (size_t)N * 64);
    float*  out2    = (float*)alloc(sizeof(float) * (size_t)N * 64);
    float*  as1     = (float*)alloc(sizeof(float) * (size_t)N * 4);
    float*  ad1     = (float*)alloc(sizeof(float) * (size_t)N * 4);
    float*  as2     = (float*)alloc(sizeof(float) * (size_t)N);
    float*  ad2     = (float*)alloc(sizeof(float) * (size_t)N);
    int*    rowstart= (int*)alloc(sizeof(int) * (size_t)(N + 1));
    int*    itmp    = (int*)alloc(sizeof(int) * (size_t)N);      // deg, then cursor
    int*    csr     = (int*)alloc(sizeof(int) * (size_t)NE);
    int*    counts  = (int*)alloc(sizeof(int) * (size_t)NG);
    int*    gstart  = (int*)alloc(sizeof(int) * (size_t)(NG + 1));
    int*    bsum    = (int*)alloc(sizeof(int) * 1024);
    int*    boff    = (int*)alloc(sizeof(int) * 1024);
    ushort* w1hi    = (ushort*)alloc(sizeof(ushort) * 32768);
    ushort* w2hi    = (ushort*)alloc(sizeof(ushort) * 16384);

    int bs = 256;
    // setup: W packs + deg/counts init
    k_setup<<<(N + bs - 1) / bs, bs, 0, stream>>>(W1, W2, w1hi, w2hi, itmp, N, counts, NG);
    k_count<<<(E + bs - 1) / bs, bs, 0, stream>>>(ei, E, itmp, batch, N, counts);
    k_scan_part<<<NB, 1024, 0, stream>>>(itmp, rowstart, bsum, N);
    k_scan_small2<<<2, 1024, 0, stream>>>(bsum, boff, NB, rowstart + N, counts, gstart, NG);
    k_scan_add_self<<<(N + 1023) / 1024, 1024, 0, stream>>>(rowstart, boff, itmp, csr, N);
    k_scatter<<<(E + bs - 1) / bs, bs, 0, stream>>>(ei, E, rowstart, itmp, csr);

    // layer 1: MFMA GEMM -> fused edgew+aggregate
    k_gemm1<<<dim3((N + 255) / 256, 2), 256, 0, stream>>>(x, w1hi, att_s1, att_d1, h1b, as1, ad1, N);
    k_fagg1<<<(N + 3) / 4, 256, 0, stream>>>(h1b, as1, ad1, rowstart, csr, b1, out1b, N);

    // layer 2
    k_gemm2<<<(N + 255) / 256, 256, 0, stream>>>(out1b, w2hi, att_s2, att_d2, h2b, as2, ad2, N);
    k_fagg2<<<(N + 3) / 4, 256, 0, stream>>>(h2b, as2, ad2, rowstart, csr, b2, out2, N);

    // pool + linear
    k_pool<<<NG, 64, 0, stream>>>(out2, gstart, lin_w, lin_b, out, NG);
}